// Round 1
// 96.559 us; speedup vs baseline: 1.0634x; 1.0634x over previous
//
#include <hip/hip_runtime.h>

#define PI_F 3.14159265358979323846f

// ---- workspace layout (floats) ----
// V01 @ 2359296  : 524288    V02 @ 2883584 : 262144    V12 @ 3145728 : 131072
// P1p @ 3276800  : 128       P2p @ 3276928 : 64

// Dirichlet interpolation tap, float-only. Integer angle reduction keeps the
// sinf/cosf arguments in [0, 2pi) (n is a power of two), so f32 is accurate.
// Analytically: Rl[0] = 1 and Rl[t] = 0 for t % s == 0 (t != 0, s = n1/n2).
// Callers exploit those exact zeros to skip whole rows/columns.
__device__ __forceinline__ float rtab_f(int n, int m2, int t) {
  if (t == 0) return 1.0f;
  int tw = 2 * n - 1;
  float th = PI_F * (float)t / (float)n;
  int A = (t * (m2 - 1)) & tw;
  int B = (t * m2) & tw;
  float v = sinf(PI_F * (float)A / (float)n) / sinf(th) +
            cosf(PI_F * (float)B / (float)n);
  return v / (float)m2;
}

// Phase-A worker: one wave computes NR interpolated rows (rls[]) of the
// upsampled map (n1 = 256 cols, float4/lane) from V rows in global memory.
// Depth-2 prefetch on the V row stream; sRl reads are wave-uniform broadcasts.
template <int NR>
__device__ __forceinline__ void phaseA256(const float* __restrict__ vch,
                                          const float* __restrict__ sRl,
                                          float* __restrict__ sh,
                                          const int (&rls)[NR], int mxg, int s,
                                          int n2, float inv, float Pv, float a,
                                          int per, int cid) {
  int bj[NR];
#pragma unroll
  for (int j = 0; j < NR; ++j) bj[j] = (mxg - 2 + rls[j]) & 255;
  float4 acc[NR];
#pragma unroll
  for (int j = 0; j < NR; ++j) acc[j] = make_float4(0.f, 0.f, 0.f, 0.f);
  const float4* vp = (const float4*)vch + cid;
  float4 va = vp[0];
  float4 vb = vp[64];
  for (int nx = 0; nx < n2; ++nx) {
    float4 vc = make_float4(0.f, 0.f, 0.f, 0.f);
    if (nx + 2 < n2) vc = vp[(size_t)(nx + 2) * 64];
    int ss = s * nx;
#pragma unroll
    for (int j = 0; j < NR; ++j) {
      float rv = sRl[(bj[j] - ss) & 255];
      acc[j].x += rv * va.x;
      acc[j].y += rv * va.y;
      acc[j].z += rv * va.z;
      acc[j].w += rv * va.w;
    }
    va = vb;
    vb = vc;
  }
  float smy[4];
#pragma unroll
  for (int j = 0; j < 4; ++j)
    smy[j] = sinf(a * (float)((4 * cid + j) & (per - 1)));
#pragma unroll
  for (int j = 0; j < NR; ++j) {
    float q = inv * sinf(a * (float)(bj[j] & (per - 1))) * Pv;
    float4 o = acc[j];
    o.x -= q * smy[0];
    o.y -= q * smy[1];
    o.z -= q * smy[2];
    o.w -= q * smy[3];
    *(float4*)&sh[rls[j] * 256 + 4 * cid] = o;
  }
}

// n1 = 128 variant (s = 2 fixed, float2 per lane over 64 lanes).
template <int NR>
__device__ __forceinline__ void phaseA128(const float* __restrict__ vch,
                                          const float* __restrict__ sRl,
                                          float* __restrict__ sh,
                                          const int (&rls)[NR], int mxg, int n2,
                                          float inv, float Pv, int cid) {
  int bj[NR];
#pragma unroll
  for (int j = 0; j < NR; ++j) bj[j] = (mxg - 2 + rls[j]) & 127;
  float2 acc[NR];
#pragma unroll
  for (int j = 0; j < NR; ++j) acc[j] = make_float2(0.f, 0.f);
  const float2* vp = (const float2*)vch + cid;
  float2 va = vp[0];
  float2 vb = vp[64];
  for (int nx = 0; nx < n2; ++nx) {
    float2 vc = make_float2(0.f, 0.f);
    if (nx + 2 < n2) vc = vp[(size_t)(nx + 2) * 64];
    int ss = 2 * nx;
#pragma unroll
    for (int j = 0; j < NR; ++j) {
      float rv = sRl[(bj[j] - ss) & 127];
      acc[j].x += rv * va.x;
      acc[j].y += rv * va.y;
    }
    va = vb;
    vb = vc;
  }
  const float a = PI_F * 0.5f;
  float smy0 = sinf(a * (float)((2 * cid) & 3));
  float smy1 = sinf(a * (float)((2 * cid + 1) & 3));
#pragma unroll
  for (int j = 0; j < NR; ++j) {
    float q = inv * sinf(a * (float)(bj[j] & 3)) * Pv;
    float2 o = acc[j];
    o.x -= q * smy0;
    o.y -= q * smy1;
    *(float2*)&sh[rls[j] * 128 + 2 * cid] = o;
  }
}

// k_front: bid 0..191 P partials; 192..319 V01 (odd cols computed, even cols
// exact copies of X1 -- Dirichlet taps vanish at even offsets); 320..447 V02;
// 448..511 V12; 512..959 self-corr groups (moved here to fill the occupancy
// bubble -- they have no dependency on V/P; out is zeroed by hipMemsetAsync).
__global__ __launch_bounds__(256) void k_front(
    const float* __restrict__ X0, const float* __restrict__ X1,
    const float* __restrict__ X2, float* __restrict__ P1p,
    float* __restrict__ P2p, float* __restrict__ V01, float* __restrict__ V02,
    float* __restrict__ V12, float* __restrict__ out) {
  __shared__ float fsm[4864];
  int bid = blockIdx.x;
  int t = threadIdx.x;
  if (bid < 192) {
    const float* X; float* P; int lg, nsp, idx0;
    if (bid < 128) { X = X1; P = P1p; lg = 7; nsp = 8; idx0 = bid; }
    else           { X = X2; P = P2p; lg = 6; nsp = 4; idx0 = bid - 128; }
    int ch = idx0 / nsp, split = idx0 % nsp;
    int n = 1 << lg;
    int total = n * n;
    int chunk = total / nsp;
    int b0 = split * chunk;
    const float* x = X + (size_t)ch * total + b0;
    float s = 0.f;
    for (int i = t; i < chunk; i += 256) {
      int idx = b0 + i;
      float v = x[i];
      s += (((idx >> lg) ^ idx) & 1) ? -v : v;
    }
#pragma unroll
    for (int off = 32; off > 0; off >>= 1) s += __shfl_down(s, off, 64);
    __shared__ float red[4];
    if ((t & 63) == 0) red[t >> 6] = s;
    __syncthreads();
    if (t == 0) P[ch * nsp + split] = red[0] + red[1] + red[2] + red[3];
    return;
  }
  if (bid < 320) {
    // ---- V01: compute odd columns only; even columns copy X1 ----
    int idx = bid - 192;
    int ch = idx >> 3, nxg = (idx & 7) * 16;
    float* Rl = fsm;
    float* Xs = fsm + 256;
    for (int i = t; i < 256; i += 256) Rl[i] = rtab_f(256, 128, i);
    const float4* xch4 =
        (const float4*)(X1 + (size_t)ch * 16384 + (size_t)nxg * 128);
    for (int i = t; i < 512; i += 256) ((float4*)Xs)[i] = xch4[i];
    __syncthreads();
    float* vch = V01 + (size_t)ch * 128 * 256;
    // even-column copies (V[nx][2k] = X1[nx][k] exactly)
    for (int i = t; i < 2048; i += 256) {
      int r = i >> 7, k = i & 127;
      vch[(size_t)(nxg + r) * 256 + 2 * k] = Xs[r * 128 + k];
    }
    int cid = t & 63, wq = t >> 6;
    int m0 = 2 * cid + 1, m1 = 2 * cid + 129;
    float acc[4][2];
#pragma unroll
    for (int r = 0; r < 4; ++r) { acc[r][0] = 0.f; acc[r][1] = 0.f; }
    for (int ny = 0; ny < 128; ++ny) {
      float r0 = Rl[(m0 - 2 * ny) & 255];
      float r1 = Rl[(m1 - 2 * ny) & 255];
#pragma unroll
      for (int r = 0; r < 4; ++r) {
        float xv = Xs[(4 * wq + r) * 128 + ny];
        acc[r][0] += xv * r0;
        acc[r][1] += xv * r1;
      }
    }
#pragma unroll
    for (int r = 0; r < 4; ++r) {
      vch[(size_t)(nxg + 4 * wq + r) * 256 + m0] = acc[r][0];
      vch[(size_t)(nxg + 4 * wq + r) * 256 + m1] = acc[r][1];
    }
    return;
  }
  if (bid < 512) {
    // ---- V02 / V12 (original full-column path) ----
    int vbid = bid - 320;
    const float* X = X2; float* V;
    int n1, n2, s, ch, nxg, colh;
    if (vbid < 128) {
      V = V02; n1 = 256; n2 = 64; s = 4;
      ch = vbid >> 3; nxg = ((vbid >> 1) & 3) * 16; colh = vbid & 1;
    } else {
      int w = vbid - 128;
      V = V12; n1 = 128; n2 = 64; s = 2;
      ch = w >> 2; nxg = (w & 3) * 16; colh = 0;
    }
    float* Rl = fsm;
    float* Xs = fsm + 256;
    for (int i = t; i < n1; i += 256) Rl[i] = rtab_f(n1, n2, i);
    const float4* xch4 =
        (const float4*)(X + (size_t)ch * n2 * n2 + (size_t)nxg * n2);
    int nx4 = (16 * n2) >> 2;
    for (int i = t; i < nx4; i += 256) ((float4*)Xs)[i] = xch4[i];
    __syncthreads();
    int myq = (t & 63) + colh * 128;
    int nxq = t >> 6;
    int mask = n1 - 1;
    float acc[4][2];
#pragma unroll
    for (int r = 0; r < 4; ++r)
#pragma unroll
      for (int c = 0; c < 2; ++c) acc[r][c] = 0.f;
    for (int ny = 0; ny < n2; ++ny) {
      float xv[4];
#pragma unroll
      for (int r = 0; r < 4; ++r) xv[r] = Xs[(4 * nxq + r) * n2 + ny];
#pragma unroll
      for (int c = 0; c < 2; ++c) {
        float rv = Rl[(myq + 64 * c - s * ny) & mask];
#pragma unroll
        for (int r = 0; r < 4; ++r) acc[r][c] += xv[r] * rv;
      }
    }
    float* vch = V + (size_t)ch * n2 * n1;
#pragma unroll
    for (int r = 0; r < 4; ++r)
      for (int c = 0; c < 2; ++c)
        vch[(size_t)(nxg + 4 * nxq + r) * n1 + myq + 64 * c] = acc[r][c];
    return;
  }
  // ---- self-corr (groups 0,3,5) ----
  int lane = t & 63;
  int wv = t >> 6;
  float accC[8][7];
#pragma unroll
  for (int i = 0; i < 8; ++i)
#pragma unroll
    for (int p = 0; p < 7; ++p) accC[i][p] = 0.f;
  int w = bid - 512;
  const float* Ab; int loc, lgn1, lgc, base;
  if (w < 256)      { loc = w;       Ab = X0; lgn1 = 8; lgc = 4; base = 0;   }
  else if (w < 384) { loc = w - 256; Ab = X1; lgn1 = 7; lgc = 3; base = 192; }
  else              { loc = w - 384; Ab = X2; lgn1 = 6; lgc = 2; base = 320; }
  int n1 = 1 << lgn1;
  int mask = n1 - 1;
  int n1sq = n1 * n1;
  int chunk = loc & ((1 << lgc) - 1);
  int bl2 = loc >> lgc;
  int b = bl2 >> 3, l2 = bl2 & 7;
  const float* A1 = Ab + (size_t)(b * 8) * n1sq;
  const float* A2 = Ab + (size_t)(b * 8 + l2) * n1sq;
  int lgtpr = lgn1 - 2;
  int tpr = 1 << lgtpr;
  int rif = 256 >> lgtpr;
  int rid = t >> lgtpr;
  int cid2 = t & (tpr - 1);
  int ty = cid2 * 4;
  int tym = (ty - 4) & mask;
  for (int rr = 0; rr < 16; rr += rif) {
    int row = chunk * 16 + rr + rid;
    const float* r0 = A2 + (size_t)row * n1;
    const float* r1 = A2 + (size_t)((row - 1) & mask) * n1;
    const float* r2 = A2 + (size_t)((row - 2) & mask) * n1;
    const float* r3 = A2 + (size_t)((row + 1) & mask) * n1;
    float4 a0 = *(const float4*)(r0 + tym);
    float4 b0 = *(const float4*)(r0 + ty);
    float4 a1 = *(const float4*)(r1 + tym);
    float4 b1 = *(const float4*)(r1 + ty);
    float4 b2 = *(const float4*)(r2 + ty);
    float4 a3 = *(const float4*)(r3 + tym);
    float4 b3 = *(const float4*)(r3 + ty);
    const float* rA = A1 + (size_t)row * n1 + ty;
#pragma unroll
    for (int l1 = 0; l1 < 8; ++l1) {
      float4 xv = *(const float4*)(rA + (size_t)l1 * n1sq);
      accC[l1][0] += xv.x * b0.x + xv.y * b0.y + xv.z * b0.z + xv.w * b0.w;
      accC[l1][1] += xv.x * a0.w + xv.y * b0.x + xv.z * b0.y + xv.w * b0.z;
      accC[l1][2] += xv.x * a0.z + xv.y * a0.w + xv.z * b0.x + xv.w * b0.y;
      accC[l1][3] += xv.x * b1.x + xv.y * b1.y + xv.z * b1.z + xv.w * b1.w;
      accC[l1][4] += xv.x * a1.w + xv.y * b1.x + xv.z * b1.y + xv.w * b1.z;
      accC[l1][5] += xv.x * b2.x + xv.y * b2.y + xv.z * b2.z + xv.w * b2.w;
      accC[l1][6] += xv.x * a3.w + xv.y * b3.x + xv.z * b3.y + xv.w * b3.z;
    }
  }
  // ---- epilogue: 2-shfl fold + LDS transpose (stride 60) ----
  float* sh = fsm;
  float* af = &accC[0][0];
#pragma unroll
  for (int j = 0; j < 56; ++j) {
    float v = af[j];
    v += __shfl_down(v, 32, 64);
    v += __shfl_down(v, 16, 64);
    af[j] = v;
  }
  __syncthreads();
  if (lane < 16) {
    float* rowp = sh + (wv * 16 + lane) * 60;
#pragma unroll
    for (int j = 0; j < 14; ++j)
      *(float4*)&rowp[4 * j] =
          make_float4(af[4 * j], af[4 * j + 1], af[4 * j + 2], af[4 * j + 3]);
  }
  __syncthreads();
  if (t < 224) {
    int v = t >> 2, q = t & 3;
    float s2 = 0.f;
#pragma unroll
    for (int i = 0; i < 16; ++i) s2 += sh[(q * 16 + i) * 60 + v];
    s2 += __shfl_down(s2, 2, 64);
    s2 += __shfl_down(s2, 1, 64);
    if (q == 0) {
      int l1o = v / 7, p = v % 7;
      atomicAdd(&out[((size_t)b * 384 + base + l1o * 8 + l2) * 7 + p], s2);
    }
  }
}

// k_main: 640 fused U+corr blocks. Phase A computes only the Dirichlet-
// nontrivial rows (odd rows for s=2: 9 of 19; 14 of 19 for s=4); rows with
// mx % s == 0 are exact copies of V rows (and have zero Nyquist correction).
__global__ __launch_bounds__(256) void k_main(const float* __restrict__ X0,
                                              const float* __restrict__ X1,
                                              const float* __restrict__ V01,
                                              const float* __restrict__ V02,
                                              const float* __restrict__ V12,
                                              const float* __restrict__ P1p,
                                              const float* __restrict__ P2p,
                                              float* __restrict__ out) {
  __shared__ float sRl[256];
  __shared__ float sh[4864];  // Us 19*256 / epilogue (time-shared)
  int u = blockIdx.x;
  int t = threadIdx.x;
  int lane = t & 63;
  int wv = t >> 6;

  float accC[8][7];
#pragma unroll
  for (int i = 0; i < 8; ++i)
#pragma unroll
    for (int p = 0; p < 7; ++p) accC[i][p] = 0.f;

  const float* V; const float* Pp; const float* A1b;
  int n1, n2, s, ch, chunk, nsp, lgn1, base; float inv;
  if (u < 256) {
    V = V01; Pp = P1p; nsp = 8; A1b = X0; n1 = 256; n2 = 128; s = 2;
    inv = 1.f / 16384.f; ch = u >> 4; chunk = u & 15; lgn1 = 8; base = 64;
  } else if (u < 512) {
    int w = u - 256;
    V = V02; Pp = P2p; nsp = 4; A1b = X0; n1 = 256; n2 = 64; s = 4;
    inv = 1.f / 4096.f; ch = w >> 4; chunk = w & 15; lgn1 = 8; base = 128;
  } else {
    int w = u - 512;
    V = V12; Pp = P2p; nsp = 4; A1b = X1; n1 = 128; n2 = 64; s = 2;
    inv = 1.f / 4096.f; ch = w >> 3; chunk = w & 7; lgn1 = 7; base = 256;
  }
  int mask = n1 - 1;
  for (int i = t; i < n1; i += 256) sRl[i] = rtab_f(n1, n2, i);
  __syncthreads();
  int mxg = chunk * 16;
  int b = ch >> 3, l2 = ch & 7;
  const float* vch = V + (size_t)ch * n2 * n1;
  float Pv = 0.f;
  for (int i = 0; i < nsp; ++i) Pv += Pp[ch * nsp + i];
  float a = PI_F / (float)s;
  int per = 2 * s;

  // ---- phase A ----
  if (n1 == 256) {
    if (s == 2) {
      if (wv < 3) {
        int rls[3] = {6 * wv + 1, 6 * wv + 3, 6 * wv + 5};
        phaseA256<3>(vch, sRl, sh, rls, mxg, 2, 128, inv, Pv, a, per, lane);
      } else {
        // 10 even rows: exact V-row copies
        for (int i = lane; i < 640; i += 64) {
          int rl = 2 * (i >> 6), c4 = (i & 63) * 4;
          int mx = (mxg - 2 + rl) & 255;
          *(float4*)&sh[rl * 256 + c4] =
              *(const float4*)(vch + (size_t)(mx >> 1) * 256 + c4);
        }
      }
    } else {  // s == 4
      if (wv == 0) {
        int rls[4] = {0, 1, 3, 4};
        phaseA256<4>(vch, sRl, sh, rls, mxg, 4, 64, inv, Pv, a, per, lane);
      } else if (wv == 1) {
        int rls[4] = {5, 7, 8, 9};
        phaseA256<4>(vch, sRl, sh, rls, mxg, 4, 64, inv, Pv, a, per, lane);
      } else if (wv == 2) {
        int rls[3] = {11, 12, 13};
        phaseA256<3>(vch, sRl, sh, rls, mxg, 4, 64, inv, Pv, a, per, lane);
      } else {
        int rls[3] = {15, 16, 17};
        phaseA256<3>(vch, sRl, sh, rls, mxg, 4, 64, inv, Pv, a, per, lane);
      }
      // 5 rows with mx%4==0: exact V-row copies (block-wide)
      for (int i = t; i < 320; i += 256) {
        int rl = 2 + 4 * (i >> 6), c4 = (i & 63) * 4;
        int mx = (mxg - 2 + rl) & 255;
        *(float4*)&sh[rl * 256 + c4] =
            *(const float4*)(vch + (size_t)(mx >> 2) * 256 + c4);
      }
    }
  } else {  // n1 == 128, s = 2
    if (wv < 3) {
      int rls[3] = {6 * wv + 1, 6 * wv + 3, 6 * wv + 5};
      phaseA128<3>(vch, sRl, sh, rls, mxg, 64, inv, Pv, lane);
    } else {
      for (int i = lane; i < 320; i += 64) {
        int rl = 2 * (i >> 5), c4 = (i & 31) * 4;
        int mx = (mxg - 2 + rl) & 127;
        *(float4*)&sh[rl * 128 + c4] =
            *(const float4*)(vch + (size_t)(mx >> 1) * 128 + c4);
      }
    }
  }
  __syncthreads();

  // ---- phase B: corr of A1 rows [mxg, mxg+16) against Us (LDS = sh) ----
  int lgtpr = lgn1 - 2;
  int tpr = 1 << lgtpr;
  int rif = 256 >> lgtpr;
  int rid = t >> lgtpr;
  int cid2 = t & (tpr - 1);
  int ty = cid2 * 4;
  int tym = (ty - 4) & mask;
  int n1sq = n1 * n1;
  const float* A1 = A1b + (size_t)(b * 8) * n1sq;
  for (int rr = 0; rr < 16; rr += rif) {
    int ri = rr + rid;
    const float* r0 = &sh[(ri + 2) * n1];
    const float* r1 = &sh[(ri + 1) * n1];
    const float* r2 = &sh[ri * n1];
    const float* r3 = &sh[(ri + 3) * n1];
    float4 a0 = *(const float4*)(r0 + tym);
    float4 b0 = *(const float4*)(r0 + ty);
    float4 a1 = *(const float4*)(r1 + tym);
    float4 b1 = *(const float4*)(r1 + ty);
    float4 b2 = *(const float4*)(r2 + ty);
    float4 a3 = *(const float4*)(r3 + tym);
    float4 b3 = *(const float4*)(r3 + ty);
    const float* rA = A1 + (size_t)(mxg + ri) * n1 + ty;
#pragma unroll
    for (int l1 = 0; l1 < 8; ++l1) {
      float4 xv = *(const float4*)(rA + (size_t)l1 * n1sq);
      accC[l1][0] += xv.x * b0.x + xv.y * b0.y + xv.z * b0.z + xv.w * b0.w;
      accC[l1][1] += xv.x * a0.w + xv.y * b0.x + xv.z * b0.y + xv.w * b0.z;
      accC[l1][2] += xv.x * a0.z + xv.y * a0.w + xv.z * b0.x + xv.w * b0.y;
      accC[l1][3] += xv.x * b1.x + xv.y * b1.y + xv.z * b1.z + xv.w * b1.w;
      accC[l1][4] += xv.x * a1.w + xv.y * b1.x + xv.z * b1.y + xv.w * b1.z;
      accC[l1][5] += xv.x * b2.x + xv.y * b2.y + xv.z * b2.z + xv.w * b2.w;
      accC[l1][6] += xv.x * a3.w + xv.y * b3.x + xv.z * b3.y + xv.w * b3.z;
    }
  }

  // ---- epilogue: 2-shfl fold + LDS transpose (stride 60) ----
  float* af = &accC[0][0];
#pragma unroll
  for (int j = 0; j < 56; ++j) {
    float v = af[j];
    v += __shfl_down(v, 32, 64);
    v += __shfl_down(v, 16, 64);
    af[j] = v;
  }
  __syncthreads();  // phase-B Us reads done before epilogue overwrites region
  if (lane < 16) {
    float* rowp = sh + (wv * 16 + lane) * 60;
#pragma unroll
    for (int j = 0; j < 14; ++j)
      *(float4*)&rowp[4 * j] =
          make_float4(af[4 * j], af[4 * j + 1], af[4 * j + 2], af[4 * j + 3]);
  }
  __syncthreads();
  if (t < 224) {
    int v = t >> 2, q = t & 3;
    float s2 = 0.f;
#pragma unroll
    for (int i = 0; i < 16; ++i) s2 += sh[(q * 16 + i) * 60 + v];
    s2 += __shfl_down(s2, 2, 64);
    s2 += __shfl_down(s2, 1, 64);
    if (q == 0) {
      int l1o = v / 7, p = v % 7;
      atomicAdd(&out[((size_t)b * 384 + base + l1o * 8 + l2) * 7 + p], s2);
    }
  }
}

extern "C" void kernel_launch(void* const* d_in, const int* in_sizes, int n_in,
                              void* d_out, int out_size, void* d_ws, size_t ws_size,
                              hipStream_t stream) {
  const float* X0 = (const float*)d_in[0];  // [2,8,256,256]
  const float* X1 = (const float*)d_in[1];  // [2,8,128,128]
  const float* X2 = (const float*)d_in[2];  // [2,8,64,64]
  float* out = (float*)d_out;               // [2,384,7]
  float* ws = (float*)d_ws;

  float* V01 = ws + 2359296;
  float* V02 = ws + 2883584;
  float* V12 = ws + 3145728;
  float* P1p = ws + 3276800;
  float* P2p = ws + 3276928;

  hipMemsetAsync(d_out, 0, (size_t)out_size, stream);
  k_front<<<960, 256, 0, stream>>>(X0, X1, X2, P1p, P2p, V01, V02, V12, out);
  k_main<<<640, 256, 0, stream>>>(X0, X1, V01, V02, V12, P1p, P2p, out);
}